// Round 18
// baseline (49.552 us; speedup 1.0000x reference)
//
#include <hip/hip_runtime.h>

// B=256, T=256, D=384, HD=64
typedef __attribute__((ext_vector_type(8))) short bf16x8;
typedef __attribute__((ext_vector_type(4))) float f32x4;

__device__ inline unsigned short f2bf(float f) {
    unsigned u = __float_as_uint(f);
    return (unsigned short)((u + 0x7fffu + ((u >> 16) & 1u)) >> 16);
}
__device__ inline void gload16(const void* g, void* l) {
    __builtin_amdgcn_global_load_lds(
        (const __attribute__((address_space(1))) unsigned*)g,
        (__attribute__((address_space(3))) unsigned*)l, 16, 0, 0);
}

// ---------------------------------------------------------------------------
// Kernel 0 (R7/R9-verified): W = [Wq;Wk;Wv] -> bf16 frag-major pre-swizzled:
//   Wp[kc*6144 + (((g*192 + col) ^ g) << 3) + kl] = W[col][kc*32 + g*8 + kl]
// ---------------------------------------------------------------------------
__global__ void wconv(const float* __restrict__ Wq, const float* __restrict__ Wk,
                      const float* __restrict__ Wv, short* __restrict__ Wp) {
    int i = blockIdx.x * 256 + threadIdx.x;
    if (i >= 192 * 384) return;
    int col = i / 384;
    int k   = i - col * 384;
    const float* src = col < 64 ? (Wq + col * 384)
                     : col < 128 ? (Wk + (col - 64) * 384)
                                 : (Wv + (col - 128) * 384);
    int kc = k >> 5, g = (k >> 3) & 3, kl = k & 7;
    Wp[kc * 6144 + (((g * 192 + col) ^ g) << 3) + kl] = (short)f2bf(src[k]);
}

// ---------------------------------------------------------------------------
// Fused kernel v9 = R17 with __launch_bounds__(1024, 4).
// R16/R17 post-mortem: VGPR_Count stuck at 64 (compiler defaulted to a
// 2-blocks/CU register target: 2048 thr/CU -> 8 waves/SIMD -> 64-VGPR cap),
// so the BK=64 pipeline's ~115 live regs spilled to scratch (WRITE_SIZE
// 16->39 MB).  LDS is 131 KB -> only 1 block/CU is ever resident, so the
// 64-reg cap bought nothing.  Declaring (1024, 4) = 4 waves/EU = exactly one
// 16-wave block per CU raises the cap to 128 VGPRs -> no spill, same
// occupancy.  Everything else (BK=64 6-step schedule, 2-set x ping-pong,
// quad x/W LDS buffers, counted vmcnt(4), raw barriers, epilogue, Q-via-Pb,
// phase-2) is R17-verbatim.
// ---------------------------------------------------------------------------
__global__ __launch_bounds__(1024, 4) void fused_attn(
    const float* __restrict__ x, const short* __restrict__ Wp,
    float* __restrict__ out) {
    __shared__ short LDSH[65536];           // 131072 B
    short* const xst = LDSH;                // 4 x 10240 sh (phase-1)
    short* const wst = LDSH + 40960;        // 4 x 6144 sh  (phase-1)
    short* const Ksh = LDSH;                // [256*72]  (phase-2 overlay)
    short* const Vt  = LDSH + 18432;        // [64*264]
    short* const Pb  = LDSH + 35328;        // [16*640]

    const int tid = threadIdx.x;
    const int wv = tid >> 6, lane = tid & 63;
    const int g = lane >> 4, c = lane & 15;
    const int b = blockIdx.x;
    const int q0 = wv * 16;

    // x staging map (R12-verbatim): thread -> rows xr0, xr0+128, chunk xc4
    const int xr0 = tid >> 3;               // 0..127
    const int xc4 = tid & 7;
    const float* gx0 = x + ((size_t)b * 256 + xr0) * 384 + xc4 * 4;
    const float* gx1 = gx0 + (size_t)128 * 384;

    f32x4 acc[12];
#pragma unroll
    for (int j = 0; j < 12; ++j) acc[j] = (f32x4){0.f, 0.f, 0.f, 0.f};

#define STAGE_W1(K)                                                           \
    if (wv < 12) gload16(Wp + (K) * 6144 + wv * 512 + lane * 8,               \
                         wst + ((K) & 3) * 6144 + wv * 512);
#define STAGE_W2(K)  STAGE_W1(K) STAGE_W1((K) + 1)
#define XWRITE(BUF, A, Bv)                                                    \
    {                                                                         \
        uint2 p0_, p1_;                                                       \
        p0_.x = (unsigned)f2bf((A).x) | ((unsigned)f2bf((A).y) << 16);        \
        p0_.y = (unsigned)f2bf((A).z) | ((unsigned)f2bf((A).w) << 16);        \
        p1_.x = (unsigned)f2bf((Bv).x) | ((unsigned)f2bf((Bv).y) << 16);      \
        p1_.y = (unsigned)f2bf((Bv).z) | ((unsigned)f2bf((Bv).w) << 16);      \
        *(uint2*)&xst[((BUF) & 3) * 10240 + xr0 * 40 + xc4 * 4] = p0_;        \
        *(uint2*)&xst[((BUF) & 3) * 10240 + (xr0 + 128) * 40 + xc4 * 4] = p1_;\
    }
#define LOADSET(P0, P1, P2, P3, K)                                            \
    P0 = *(const float4*)(gx0 + (K) * 32);                                    \
    P1 = *(const float4*)(gx1 + (K) * 32);                                    \
    P2 = *(const float4*)(gx0 + ((K) + 1) * 32);                              \
    P3 = *(const float4*)(gx1 + ((K) + 1) * 32);
#define WRITESET(P0, P1, P2, P3, K)                                           \
    XWRITE((K), P0, P1) XWRITE((K) + 1, P2, P3)
#define COMPUTE1(K)                                                           \
    {                                                                         \
        const short* xb = xst + ((K) & 3) * 10240;                            \
        const short* wb = wst + ((K) & 3) * 6144;                             \
        bf16x8 af = *(const bf16x8*)&xb[(q0 + c) * 40 + g * 8];               \
        _Pragma("unroll")                                                     \
        for (int h_ = 0; h_ < 2; ++h_) {                                      \
            bf16x8 bfr[6];                                                    \
            _Pragma("unroll")                                                 \
            for (int j6 = 0; j6 < 6; ++j6) {                                  \
                int col = (h_ * 6 + j6) * 16 + c;                             \
                bfr[j6] = *(const bf16x8*)&wb[((g * 192 + col) ^ g) << 3];    \
            }                                                                 \
            _Pragma("unroll")                                                 \
            for (int j6 = 0; j6 < 6; ++j6)                                    \
                acc[h_ * 6 + j6] = __builtin_amdgcn_mfma_f32_16x16x32_bf16(   \
                    af, bfr[j6], acc[h_ * 6 + j6], 0, 0, 0);                  \
        }                                                                     \
    }
#define COMPUTE2(K)  COMPUTE1(K) COMPUTE1((K) + 1)
#define ENDSTEP(N)                                                            \
    asm volatile("s_waitcnt vmcnt(" #N ")" ::: "memory");                     \
    asm volatile("s_waitcnt lgkmcnt(0)" ::: "memory");                        \
    __builtin_amdgcn_s_barrier();                                             \
    __builtin_amdgcn_sched_barrier(0);

    float4 xP0, xP1, xP2, xP3, xQ0, xQ1, xQ2, xQ3;

    // ---- prologue: P<-chunks 0,1; W0,1; Q<-chunks 2,3; write P; barrier ----
    LOADSET(xP0, xP1, xP2, xP3, 0)
    __builtin_amdgcn_sched_barrier(0);
    STAGE_W2(0)
    __builtin_amdgcn_sched_barrier(0);
    LOADSET(xQ0, xQ1, xQ2, xQ3, 2)
    __builtin_amdgcn_sched_barrier(0);
    WRITESET(xP0, xP1, xP2, xP3, 0)        // implicit wait drains P only
    ENDSTEP(4)                              // drains W0,1; Q stays in flight

    // ---- 6 steps (consume chunks 2s,2s+1); cur/next ping-pong P<->Q ----
    // s=0: cur=Q(2,3), next=P<-(4,5)
    STAGE_W2(2)
    __builtin_amdgcn_sched_barrier(0);
    LOADSET(xP0, xP1, xP2, xP3, 4)
    __builtin_amdgcn_sched_barrier(0);
    COMPUTE2(0)
    WRITESET(xQ0, xQ1, xQ2, xQ3, 2)
    ENDSTEP(4)
    // s=1: cur=P(4,5), next=Q<-(6,7)
    STAGE_W2(4)
    __builtin_amdgcn_sched_barrier(0);
    LOADSET(xQ0, xQ1, xQ2, xQ3, 6)
    __builtin_amdgcn_sched_barrier(0);
    COMPUTE2(2)
    WRITESET(xP0, xP1, xP2, xP3, 4)
    ENDSTEP(4)
    // s=2: cur=Q(6,7), next=P<-(8,9)
    STAGE_W2(6)
    __builtin_amdgcn_sched_barrier(0);
    LOADSET(xP0, xP1, xP2, xP3, 8)
    __builtin_amdgcn_sched_barrier(0);
    COMPUTE2(4)
    WRITESET(xQ0, xQ1, xQ2, xQ3, 6)
    ENDSTEP(4)
    // s=3: cur=P(8,9), next=Q<-(10,11)
    STAGE_W2(8)
    __builtin_amdgcn_sched_barrier(0);
    LOADSET(xQ0, xQ1, xQ2, xQ3, 10)
    __builtin_amdgcn_sched_barrier(0);
    COMPUTE2(6)
    WRITESET(xP0, xP1, xP2, xP3, 8)
    ENDSTEP(4)
    // s=4: cur=Q(10,11); no next-load; drain all
    STAGE_W2(10)
    __builtin_amdgcn_sched_barrier(0);
    COMPUTE2(8)
    WRITESET(xQ0, xQ1, xQ2, xQ3, 10)
    ENDSTEP(0)
    // s=5: consume 10,11
    COMPUTE2(10)
    __syncthreads();

    // ---- epilogue (R12-verbatim): acc -> K/V LDS; Q -> regs via per-wave Pb.
    // C/D layout (verified): within 16x16 tile, col = c, row = 4g + r.
    short* const pbw = Pb + wv * 640;
    bf16x8 qf0, qf1;
    {
#pragma unroll
        for (int r = 0; r < 4; ++r) {
            pbw[(4 * g + r) * 40 + c]      = (short)f2bf(acc[0][r]);
            pbw[(4 * g + r) * 40 + 16 + c] = (short)f2bf(acc[1][r]);
        }
        qf0 = *(const bf16x8*)&pbw[c * 40 + g * 8];
#pragma unroll
        for (int r = 0; r < 4; ++r) {
            pbw[(4 * g + r) * 40 + c]      = (short)f2bf(acc[2][r]);
            pbw[(4 * g + r) * 40 + 16 + c] = (short)f2bf(acc[3][r]);
        }
        qf1 = *(const bf16x8*)&pbw[c * 40 + g * 8];
    }
#pragma unroll
    for (int nj = 4; nj < 8; ++nj) {
        const int row = q0 + 4 * g;
#pragma unroll
        for (int r = 0; r < 4; ++r)
            Ksh[(row + r) * 72 + (nj - 4) * 16 + c] = (short)f2bf(acc[nj][r]);
    }
#pragma unroll
    for (int nj = 8; nj < 12; ++nj) {
        const int h = (nj - 8) * 16 + c;
        const int swz = ((h >> 3) & 7) << 3;
        const int row = q0 + 4 * g;
#pragma unroll
        for (int r = 0; r < 4; ++r)
            Vt[(h * 264 + row + r) ^ swz] = (short)f2bf(acc[nj][r]);
    }
    __syncthreads();

    // ---------------- Phase 2: causal attention (R12-verbatim) --------------
    {
        f32x4 o[4];
#pragma unroll
        for (int nj = 0; nj < 4; ++nj) o[nj] = (f32x4){0.f, 0.f, 0.f, 0.f};
        float m[4] = {-INFINITY, -INFINITY, -INFINITY, -INFINITY};
        float ls[4] = {0.f, 0.f, 0.f, 0.f};
        const int jmax = (q0 + 15) >> 5;

        for (int j = 0; j <= jmax; ++j) {
            f32x4 s0 = {0.f, 0.f, 0.f, 0.f}, s1 = {0.f, 0.f, 0.f, 0.f};
            {
                bf16x8 kf;
                kf = *(const bf16x8*)&Ksh[(32 * j + c) * 72 + g * 8];
                s0 = __builtin_amdgcn_mfma_f32_16x16x32_bf16(qf0, kf, s0, 0, 0, 0);
                kf = *(const bf16x8*)&Ksh[(32 * j + c) * 72 + 32 + g * 8];
                s0 = __builtin_amdgcn_mfma_f32_16x16x32_bf16(qf1, kf, s0, 0, 0, 0);
                kf = *(const bf16x8*)&Ksh[(32 * j + 16 + c) * 72 + g * 8];
                s1 = __builtin_amdgcn_mfma_f32_16x16x32_bf16(qf0, kf, s1, 0, 0, 0);
                kf = *(const bf16x8*)&Ksh[(32 * j + 16 + c) * 72 + 32 + g * 8];
                s1 = __builtin_amdgcn_mfma_f32_16x16x32_bf16(qf1, kf, s1, 0, 0, 0);
            }
            float t0[4], t1[4];
#pragma unroll
            for (int r = 0; r < 4; ++r) {
                t0[r] = s0[r] * 0.125f;
                t1[r] = s1[r] * 0.125f;
            }
            if (j == jmax) {   // wave-uniform: diagonal tile, causal mask
                int q = q0 + 4 * g;
#pragma unroll
                for (int r = 0; r < 4; ++r) {
                    if (32 * j + c > q + r) t0[r] = -INFINITY;
                    if (32 * j + 16 + c > q + r) t1[r] = -INFINITY;
                }
            }
            float corr[4], p0[4], p1[4];
#pragma unroll
            for (int r = 0; r < 4; ++r) {
                float v = fmaxf(t0[r], t1[r]);
#pragma unroll
                for (int off = 1; off < 16; off <<= 1) v = fmaxf(v, __shfl_xor(v, off, 16));
                float mn = fmaxf(m[r], v);
                corr[r] = __expf(m[r] - mn);   // first tile: exp(-inf)=0
                m[r] = mn;
                p0[r] = __expf(t0[r] - mn);
                p1[r] = __expf(t1[r] - mn);
                float rs = p0[r] + p1[r];
#pragma unroll
                for (int off = 1; off < 16; off <<= 1) rs += __shfl_xor(rs, off, 16);
                ls[r] = ls[r] * corr[r] + rs;
            }
#pragma unroll
            for (int nj = 0; nj < 4; ++nj) {
                f32x4 t = o[nj];
                t[0] *= corr[0]; t[1] *= corr[1]; t[2] *= corr[2]; t[3] *= corr[3];
                o[nj] = t;
            }
            // P -> Pb (C/D rows) -> A-frag read (same-wave RAW, in-order LDS)
#pragma unroll
            for (int r = 0; r < 4; ++r) {
                pbw[(4 * g + r) * 40 + c]      = (short)f2bf(p0[r]);
                pbw[(4 * g + r) * 40 + 16 + c] = (short)f2bf(p1[r]);
            }
            bf16x8 pfa = *(const bf16x8*)&pbw[c * 40 + g * 8];
#pragma unroll
            for (int nj = 0; nj < 4; ++nj) {
                int h = 16 * nj + c;
                int swz = ((2 * nj + (c >> 3)) & 7) << 3;
                bf16x8 vf = *(const bf16x8*)&Vt[(h * 264 + 32 * j + g * 8) ^ swz];
                o[nj] = __builtin_amdgcn_mfma_f32_16x16x32_bf16(pfa, vf, o[nj], 0, 0, 0);
            }
        }
        float inv[4];
#pragma unroll
        for (int r = 0; r < 4; ++r) inv[r] = 1.f / ls[r];
        float* ob = out + ((size_t)b * 256 + q0) * 64;
#pragma unroll
        for (int nj = 0; nj < 4; ++nj)
#pragma unroll
            for (int r = 0; r < 4; ++r)
                ob[(4 * g + r) * 64 + 16 * nj + c] = o[nj][r] * inv[r];
    }
#undef STAGE_W1
#undef STAGE_W2
#undef XWRITE
#undef LOADSET
#undef WRITESET
#undef COMPUTE1
#undef COMPUTE2
#undef ENDSTEP
}

// ---------------------------------------------------------------------------
extern "C" void kernel_launch(void* const* d_in, const int* in_sizes, int n_in,
                              void* d_out, int out_size, void* d_ws, size_t ws_size,
                              hipStream_t stream) {
    const float* x  = (const float*)d_in[0];
    const float* Wq = (const float*)d_in[1];
    const float* Wk = (const float*)d_in[2];
    const float* Wv = (const float*)d_in[3];
    float* out = (float*)d_out;

    short* Wp = (short*)d_ws;   // 73728 shorts (144 KB)

    wconv<<<dim3(288), dim3(256), 0, stream>>>(Wq, Wk, Wv, Wp);
    fused_attn<<<dim3(256), dim3(1024), 0, stream>>>(x, Wp, out);
}

// Round 19
// 41.891 us; speedup vs baseline: 1.1829x; 1.1829x over previous
//
#include <hip/hip_runtime.h>

// B=256, T=256, D=384, HD=64
typedef __attribute__((ext_vector_type(8))) short bf16x8;
typedef __attribute__((ext_vector_type(4))) float f32x4;

__device__ inline unsigned short f2bf(float f) {
    unsigned u = __float_as_uint(f);
    return (unsigned short)((u + 0x7fffu + ((u >> 16) & 1u)) >> 16);
}
__device__ inline void gload16(const void* g, void* l) {
    __builtin_amdgcn_global_load_lds(
        (const __attribute__((address_space(1))) unsigned*)g,
        (__attribute__((address_space(3))) unsigned*)l, 16, 0, 0);
}

// ---------------------------------------------------------------------------
// Kernel 0 (R7/R9-verified): W = [Wq;Wk;Wv] -> bf16 frag-major pre-swizzled:
//   Wp[kc*6144 + (((g*192 + col) ^ g) << 3) + kl] = W[col][kc*32 + g*8 + kl]
// ---------------------------------------------------------------------------
__global__ void wconv(const float* __restrict__ Wq, const float* __restrict__ Wk,
                      const float* __restrict__ Wv, short* __restrict__ Wp) {
    int i = blockIdx.x * 256 + threadIdx.x;
    if (i >= 192 * 384) return;
    int col = i / 384;
    int k   = i - col * 384;
    const float* src = col < 64 ? (Wq + col * 384)
                     : col < 128 ? (Wk + (col - 64) * 384)
                                 : (Wv + (col - 128) * 384);
    int kc = k >> 5, g = (k >> 3) & 3, kl = k & 7;
    Wp[kc * 6144 + (((g * 192 + col) ^ g) << 3) + kl] = (short)f2bf(src[k]);
}

// ---------------------------------------------------------------------------
// Fused kernel v10: the untested cell of the {barriers?, W-source} matrix:
// NO in-loop barriers + W from LDS.  R14 failed with W on the VMEM path;
// R12/R13's residual was the 12-step barrier convoy (waves inherit the
// slowest chain each step; wave-TLP forbidden).  Enabler: the ENTIRE
// pre-packed Wp (144 KB) fits in LDS -> stage it ONCE in the prologue
// (9 gload16/wave + one barrier); the k-loop is then completely
// data-flow (x direct-to-reg wave-private triple-set, W ds_read_b128).
// 16 waves free-run; TLP hides x L3 latency (m114 mechanism).
// Phase-1 has exactly 2 barriers.  Phase-2 overlays the W region after the
// epilogue sync; epilogue + Q-via-Pb + attention are R13-verbatim.
// Register profile == R13 (~56 VGPR, acc in AGPRs) -> no spill at the
// 1024-thread 64-VGPR cap.  LDS 147456 B < 160 KB, 1 block/CU.
// ---------------------------------------------------------------------------
__global__ __launch_bounds__(1024) void fused_attn(
    const float* __restrict__ x, const short* __restrict__ Wp,
    float* __restrict__ out) {
    __shared__ short LDSH[73728];           // 147456 B
    short* const Wlds = LDSH;               // 12*6144 shorts (phase-1)
    short* const Ksh  = LDSH;               // [256*72]  (phase-2 overlay)
    short* const Vt   = LDSH + 18432;       // [64*264]
    short* const Pb   = LDSH + 35328;       // [16*640]

    const int tid = threadIdx.x;
    const int wv = tid >> 6, lane = tid & 63;
    const int g = lane >> 4, c = lane & 15;
    const int b = blockIdx.x;
    const int q0 = wv * 16;

    // direct x addressing: lane (g,c) of wave wv reads row q0+c, cols s*32+g*8
    const float* gxw = x + ((size_t)b * 256 + q0 + c) * 384 + g * 8;

    f32x4 acc[12];
#pragma unroll
    for (int j = 0; j < 12; ++j) acc[j] = (f32x4){0.f, 0.f, 0.f, 0.f};

    // ---- prologue: stage ALL of Wp (144 KB) into LDS; one barrier ----
#pragma unroll
    for (int r = 0; r < 9; ++r) {
        int seg = r * 16 + wv;              // 0..143 segments of 1 KB
        gload16(Wp + seg * 512 + lane * 8, Wlds + seg * 512);
    }
    __syncthreads();                        // drains gloads; Wlds visible

#define COMPUTE(S, F0, F1)                                                    \
    {                                                                         \
        const short* wb = Wlds + (S) * 6144;                                  \
        bf16x8 af;                                                            \
        af[0] = (short)f2bf((F0).x); af[1] = (short)f2bf((F0).y);             \
        af[2] = (short)f2bf((F0).z); af[3] = (short)f2bf((F0).w);             \
        af[4] = (short)f2bf((F1).x); af[5] = (short)f2bf((F1).y);             \
        af[6] = (short)f2bf((F1).z); af[7] = (short)f2bf((F1).w);             \
        _Pragma("unroll")                                                     \
        for (int h_ = 0; h_ < 2; ++h_) {                                      \
            bf16x8 bfr[6];                                                    \
            _Pragma("unroll")                                                 \
            for (int j6 = 0; j6 < 6; ++j6) {                                  \
                int col = (h_ * 6 + j6) * 16 + c;                             \
                bfr[j6] = *(const bf16x8*)&wb[((g * 192 + col) ^ g) << 3];    \
            }                                                                 \
            _Pragma("unroll")                                                 \
            for (int j6 = 0; j6 < 6; ++j6)                                    \
                acc[h_ * 6 + j6] = __builtin_amdgcn_mfma_f32_16x16x32_bf16(   \
                    af, bfr[j6], acc[h_ * 6 + j6], 0, 0, 0);                  \
        }                                                                     \
    }
// STEP(S): issue x(S+2) into LD set; compute S from CUR set.  Pure data
// flow -- no barriers, no asm waits; compiler pipelines, waves free-run.
#define STEP(S, LD0, LD1, CUR0, CUR1)                                        \
    {                                                                        \
        if ((S) <= 9) {                                                      \
            LD0 = *(const float4*)(gxw + ((S) + 2) * 32);                    \
            LD1 = *(const float4*)(gxw + ((S) + 2) * 32 + 4);                 \
        }                                                                    \
        COMPUTE(S, CUR0, CUR1)                                               \
    }

    float4 xA0, xA1, xB0, xB1, xC0, xC1;
    xA0 = *(const float4*)(gxw);
    xA1 = *(const float4*)(gxw + 4);
    xB0 = *(const float4*)(gxw + 32);
    xB1 = *(const float4*)(gxw + 36);

    STEP(0,  xC0, xC1, xA0, xA1)
    STEP(1,  xA0, xA1, xB0, xB1)
    STEP(2,  xB0, xB1, xC0, xC1)
    STEP(3,  xC0, xC1, xA0, xA1)
    STEP(4,  xA0, xA1, xB0, xB1)
    STEP(5,  xB0, xB1, xC0, xC1)
    STEP(6,  xC0, xC1, xA0, xA1)
    STEP(7,  xA0, xA1, xB0, xB1)
    STEP(8,  xB0, xB1, xC0, xC1)
    STEP(9,  xC0, xC1, xA0, xA1)
    STEP(10, xA0, xA1, xB0, xB1)
    COMPUTE(11, xC0, xC1)
    __syncthreads();                        // all Wlds reads done (overlay)

    // ---- epilogue (R13-verbatim): acc -> K/V LDS; Q -> regs via Pb.
    // C/D layout (verified): within 16x16 tile, col = c, row = 4g + r.
    short* const pbw = Pb + wv * 640;
    bf16x8 qf0, qf1;
    {
#pragma unroll
        for (int r = 0; r < 4; ++r) {
            pbw[(4 * g + r) * 40 + c]      = (short)f2bf(acc[0][r]);
            pbw[(4 * g + r) * 40 + 16 + c] = (short)f2bf(acc[1][r]);
        }
        qf0 = *(const bf16x8*)&pbw[c * 40 + g * 8];
#pragma unroll
        for (int r = 0; r < 4; ++r) {
            pbw[(4 * g + r) * 40 + c]      = (short)f2bf(acc[2][r]);
            pbw[(4 * g + r) * 40 + 16 + c] = (short)f2bf(acc[3][r]);
        }
        qf1 = *(const bf16x8*)&pbw[c * 40 + g * 8];
    }
#pragma unroll
    for (int nj = 4; nj < 8; ++nj) {
        const int row = q0 + 4 * g;
#pragma unroll
        for (int r = 0; r < 4; ++r)
            Ksh[(row + r) * 72 + (nj - 4) * 16 + c] = (short)f2bf(acc[nj][r]);
    }
#pragma unroll
    for (int nj = 8; nj < 12; ++nj) {
        const int h = (nj - 8) * 16 + c;
        const int swz = ((h >> 3) & 7) << 3;
        const int row = q0 + 4 * g;
#pragma unroll
        for (int r = 0; r < 4; ++r)
            Vt[(h * 264 + row + r) ^ swz] = (short)f2bf(acc[nj][r]);
    }
    __syncthreads();

    // ---------------- Phase 2: causal attention (R13-verbatim) --------------
    {
        f32x4 o[4];
#pragma unroll
        for (int nj = 0; nj < 4; ++nj) o[nj] = (f32x4){0.f, 0.f, 0.f, 0.f};
        float m[4] = {-INFINITY, -INFINITY, -INFINITY, -INFINITY};
        float ls[4] = {0.f, 0.f, 0.f, 0.f};
        const int jmax = (q0 + 15) >> 5;

        for (int j = 0; j <= jmax; ++j) {
            f32x4 s0 = {0.f, 0.f, 0.f, 0.f}, s1 = {0.f, 0.f, 0.f, 0.f};
            {
                bf16x8 kf;
                kf = *(const bf16x8*)&Ksh[(32 * j + c) * 72 + g * 8];
                s0 = __builtin_amdgcn_mfma_f32_16x16x32_bf16(qf0, kf, s0, 0, 0, 0);
                kf = *(const bf16x8*)&Ksh[(32 * j + c) * 72 + 32 + g * 8];
                s0 = __builtin_amdgcn_mfma_f32_16x16x32_bf16(qf1, kf, s0, 0, 0, 0);
                kf = *(const bf16x8*)&Ksh[(32 * j + 16 + c) * 72 + g * 8];
                s1 = __builtin_amdgcn_mfma_f32_16x16x32_bf16(qf0, kf, s1, 0, 0, 0);
                kf = *(const bf16x8*)&Ksh[(32 * j + 16 + c) * 72 + 32 + g * 8];
                s1 = __builtin_amdgcn_mfma_f32_16x16x32_bf16(qf1, kf, s1, 0, 0, 0);
            }
            float t0[4], t1[4];
#pragma unroll
            for (int r = 0; r < 4; ++r) {
                t0[r] = s0[r] * 0.125f;
                t1[r] = s1[r] * 0.125f;
            }
            if (j == jmax) {   // wave-uniform: diagonal tile, causal mask
                int q = q0 + 4 * g;
#pragma unroll
                for (int r = 0; r < 4; ++r) {
                    if (32 * j + c > q + r) t0[r] = -INFINITY;
                    if (32 * j + 16 + c > q + r) t1[r] = -INFINITY;
                }
            }
            float corr[4], p0[4], p1[4];
#pragma unroll
            for (int r = 0; r < 4; ++r) {
                float v = fmaxf(t0[r], t1[r]);
#pragma unroll
                for (int off = 1; off < 16; off <<= 1) v = fmaxf(v, __shfl_xor(v, off, 16));
                float mn = fmaxf(m[r], v);
                corr[r] = __expf(m[r] - mn);   // first tile: exp(-inf)=0
                m[r] = mn;
                p0[r] = __expf(t0[r] - mn);
                p1[r] = __expf(t1[r] - mn);
                float rs = p0[r] + p1[r];
#pragma unroll
                for (int off = 1; off < 16; off <<= 1) rs += __shfl_xor(rs, off, 16);
                ls[r] = ls[r] * corr[r] + rs;
            }
#pragma unroll
            for (int nj = 0; nj < 4; ++nj) {
                f32x4 t = o[nj];
                t[0] *= corr[0]; t[1] *= corr[1]; t[2] *= corr[2]; t[3] *= corr[3];
                o[nj] = t;
            }
            // P -> Pb (C/D rows) -> A-frag read (same-wave RAW, in-order LDS)
#pragma unroll
            for (int r = 0; r < 4; ++r) {
                pbw[(4 * g + r) * 40 + c]      = (short)f2bf(p0[r]);
                pbw[(4 * g + r) * 40 + 16 + c] = (short)f2bf(p1[r]);
            }
            bf16x8 pfa = *(const bf16x8*)&pbw[c * 40 + g * 8];
#pragma unroll
            for (int nj = 0; nj < 4; ++nj) {
                int h = 16 * nj + c;
                int swz = ((2 * nj + (c >> 3)) & 7) << 3;
                bf16x8 vf = *(const bf16x8*)&Vt[(h * 264 + 32 * j + g * 8) ^ swz];
                o[nj] = __builtin_amdgcn_mfma_f32_16x16x32_bf16(pfa, vf, o[nj], 0, 0, 0);
            }
        }
        float inv[4];
#pragma unroll
        for (int r = 0; r < 4; ++r) inv[r] = 1.f / ls[r];
        float* ob = out + ((size_t)b * 256 + q0) * 64;
#pragma unroll
        for (int nj = 0; nj < 4; ++nj)
#pragma unroll
            for (int r = 0; r < 4; ++r)
                ob[(4 * g + r) * 64 + 16 * nj + c] = o[nj][r] * inv[r];
    }
#undef COMPUTE
#undef STEP
}

// ---------------------------------------------------------------------------
extern "C" void kernel_launch(void* const* d_in, const int* in_sizes, int n_in,
                              void* d_out, int out_size, void* d_ws, size_t ws_size,
                              hipStream_t stream) {
    const float* x  = (const float*)d_in[0];
    const float* Wq = (const float*)d_in[1];
    const float* Wk = (const float*)d_in[2];
    const float* Wv = (const float*)d_in[3];
    float* out = (float*)d_out;

    short* Wp = (short*)d_ws;   // 73728 shorts (144 KB)

    wconv<<<dim3(288), dim3(256), 0, stream>>>(Wq, Wk, Wv, Wp);
    fused_attn<<<dim3(256), dim3(1024), 0, stream>>>(x, Wp, out);
}